// Round 1
// baseline (2457.714 us; speedup 1.0000x reference)
//
#include <hip/hip_runtime.h>
#include <hip/hip_bf16.h>
#include <math.h>

typedef unsigned short u16;
typedef __attribute__((ext_vector_type(8))) short short8;
typedef __attribute__((ext_vector_type(4))) float f32x4;
typedef __attribute__((ext_vector_type(4))) unsigned short u16x4;

constexpr int T_   = 32768;
constexpr int D_   = 1024;
constexpr int H_   = 2048;
constexpr int OUT_ = 1024;
constexpr int E_   = 8;
constexpr int MAXTILES_ = 1040;

__device__ __forceinline__ u16 f2bf(float f) {
    unsigned u = __float_as_uint(f);
    u += 0x7FFFu + ((u >> 16) & 1u);
    return (u16)(u >> 16);
}

__device__ __forceinline__ void gload_lds16(const u16* g, u16* l) {
    __builtin_amdgcn_global_load_lds(
        (const __attribute__((address_space(1))) unsigned int*)g,
        (__attribute__((address_space(3))) unsigned int*)l, 16, 0, 0);
}

__device__ __forceinline__ float gelu_exact(float v) {
    return 0.5f * v * (1.0f + erff(v * 0.70710678118654752f));
}

// ---------------------------------------------------------------------------
// Kernel 1: fused LayerNorm + router. Block = 4 rows (1/wave).
// ---------------------------------------------------------------------------
__global__ __launch_bounds__(256) void ln_router_kernel(
    const float* __restrict__ x, const float* __restrict__ gamma,
    const float* __restrict__ beta, const float* __restrict__ rw,
    const float* __restrict__ rb, u16* __restrict__ xn,
    unsigned* __restrict__ topk_idx, float* __restrict__ topk_gate)
{
    __shared__ float xn_lds[4 * 1024];     // 16 KB
    __shared__ float rwT[8 * 1024];        // 32 KB
    __shared__ float plog[4 * 32 * 8];     // 4 KB  [row][slot][e]

    const int tid  = threadIdx.x;
    const int lane = tid & 63;
    const int wave = tid >> 6;
    const int row  = blockIdx.x * 4 + wave;
    const float* xr = x + (size_t)row * D_;

    // stage rw -> rwT (transposed), coalesced global float4 reads
#pragma unroll
    for (int it = 0; it < 8; ++it) {
        const int f0 = it * 1024 + tid * 4;
        float4 v4 = *(const float4*)(rw + f0);
        const int d  = f0 >> 3;
        const int e0 = (tid & 1) * 4;
        rwT[(e0 + 0) * 1024 + d] = v4.x;
        rwT[(e0 + 1) * 1024 + d] = v4.y;
        rwT[(e0 + 2) * 1024 + d] = v4.z;
        rwT[(e0 + 3) * 1024 + d] = v4.w;
    }

    // Phase A: LN
    float v[16];
#pragma unroll
    for (int j = 0; j < 4; ++j) {
        float4 t = *(const float4*)(xr + (j * 64 + lane) * 4);
        v[j*4+0] = t.x; v[j*4+1] = t.y; v[j*4+2] = t.z; v[j*4+3] = t.w;
    }
    float s = 0.f, ss = 0.f;
#pragma unroll
    for (int i = 0; i < 16; ++i) { s += v[i]; ss += v[i] * v[i]; }
#pragma unroll
    for (int st = 32; st > 0; st >>= 1) { s += __shfl_xor(s, st); ss += __shfl_xor(ss, st); }
    const float mu   = s * (1.0f / 1024.0f);
    const float var  = ss * (1.0f / 1024.0f) - mu * mu;
    const float rstd = rsqrtf(var + 1e-5f);

#pragma unroll
    for (int j = 0; j < 4; ++j) {
        const int d0 = (j * 64 + lane) * 4;
        float4 g4 = *(const float4*)(gamma + d0);
        float4 b4 = *(const float4*)(beta + d0);
        f32x4 xnv;
        xnv[0] = (v[j*4+0] - mu) * rstd * g4.x + b4.x;
        xnv[1] = (v[j*4+1] - mu) * rstd * g4.y + b4.y;
        xnv[2] = (v[j*4+2] - mu) * rstd * g4.z + b4.z;
        xnv[3] = (v[j*4+3] - mu) * rstd * g4.w + b4.w;
        *(f32x4*)(xn_lds + wave * 1024 + d0) = xnv;
        u16x4 pk;
        pk.x = f2bf(xnv[0]); pk.y = f2bf(xnv[1]);
        pk.z = f2bf(xnv[2]); pk.w = f2bf(xnv[3]);
        *(u16x4*)(xn + (size_t)row * D_ + d0) = pk;
    }
    __syncthreads();

    // Phase B: lane -> (e = lane>>3, dseg = lane&7)
    const int e    = lane >> 3;
    const int dseg = lane & 7;
    float part[4] = {0.f, 0.f, 0.f, 0.f};
#pragma unroll
    for (int ii = 0; ii < 8; ++ii) {
        const int q = dseg + (wave * 8 + ii) * 8;      // quad index 0..255
        f32x4 rw4 = *(const f32x4*)(rwT + e * 1024 + q * 4);
#pragma unroll
        for (int r = 0; r < 4; ++r) {
            f32x4 x4 = *(const f32x4*)(xn_lds + r * 1024 + q * 4);
            part[r] += x4[0]*rw4[0] + x4[1]*rw4[1] + x4[2]*rw4[2] + x4[3]*rw4[3];
        }
    }
#pragma unroll
    for (int r = 0; r < 4; ++r)
        plog[(r * 32 + wave * 8 + dseg) * 8 + e] = part[r];
    __syncthreads();

    const int rr = wave;
    const int ee = (lane >> 3) & 7;
    const int s8 = lane & 7;
    float val = plog[(rr * 32 + s8) * 8 + ee] + plog[(rr * 32 + s8 + 8) * 8 + ee]
              + plog[(rr * 32 + s8 + 16) * 8 + ee] + plog[(rr * 32 + s8 + 24) * 8 + ee];
    val += __shfl_xor(val, 1);
    val += __shfl_xor(val, 2);
    val += __shfl_xor(val, 4);
    val += rb[ee];

    float vv[8];
#pragma unroll
    for (int k = 0; k < 8; ++k) vv[k] = __shfl(val, k * 8);

    if (lane == 0) {
        unsigned used = 0, pack = 0;
        float tv[4];
#pragma unroll
        for (int k = 0; k < 4; ++k) {
            float best = -3.4e38f; int bi = 0;
#pragma unroll
            for (int q = 0; q < 8; ++q)
                if (!((used >> q) & 1) && vv[q] > best) { best = vv[q]; bi = q; }
            used |= 1u << bi; tv[k] = best; pack |= (unsigned)bi << (8 * k);
        }
        float ex[4], sum = 0.f;
#pragma unroll
        for (int k = 0; k < 4; ++k) { ex[k] = expf(tv[k] - tv[0]); sum += ex[k]; }
        const float inv = 1.0f / sum;
        topk_idx[row] = pack;
#pragma unroll
        for (int k = 0; k < 4; ++k) topk_gate[row * 4 + k] = ex[k] * inv;
    }
}

// ---------------------------------------------------------------------------
// Kernel 2: transpose+convert weights to bf16 B^T (k-contiguous) layout.
// ---------------------------------------------------------------------------
__global__ __launch_bounds__(256) void transpose_cvt_kernel(
    const float* __restrict__ w1, const float* __restrict__ w2,
    u16* __restrict__ w1t, u16* __restrict__ w2t)
{
    __shared__ float lds[32][33];
    int t = blockIdx.x;
    const float* src; u16* dst; int R, C, rt, ct;
    if (t < 16384) {
        int e = t >> 11, loc = t & 2047;
        rt = loc >> 6; ct = loc & 63;
        src = w1 + (size_t)e * D_ * H_; dst = w1t + (size_t)e * D_ * H_;
        R = D_; C = H_;
    } else {
        t -= 16384;
        int e = t >> 11, loc = t & 2047;
        rt = loc >> 5; ct = loc & 31;
        src = w2 + (size_t)e * H_ * OUT_; dst = w2t + (size_t)e * H_ * OUT_;
        R = H_; C = OUT_;
    }
    const int r  = threadIdx.x >> 3;
    const int c4 = (threadIdx.x & 7) * 4;
    float4 val = *(const float4*)(src + (size_t)(rt * 32 + r) * C + ct * 32 + c4);
    lds[r][c4+0] = val.x; lds[r][c4+1] = val.y; lds[r][c4+2] = val.z; lds[r][c4+3] = val.w;
    __syncthreads();
    const int cc = threadIdx.x >> 3;
    const int r4 = (threadIdx.x & 7) * 4;
    u16x4 o;
    o.x = f2bf(lds[r4+0][cc]); o.y = f2bf(lds[r4+1][cc]);
    o.z = f2bf(lds[r4+2][cc]); o.w = f2bf(lds[r4+3][cc]);
    *(u16x4*)(dst + (size_t)(ct * 32 + cc) * R + rt * 32 + r4) = o;
}

// ---------------------------------------------------------------------------
// Kernel 3: build per-expert compacted (token, gate) pair lists.
// ---------------------------------------------------------------------------
__global__ __launch_bounds__(256) void pair_build_kernel(
    const unsigned* __restrict__ topk_idx, const float* __restrict__ topk_gate,
    int* __restrict__ pair_tok, float* __restrict__ pair_gate, int* __restrict__ gcount)
{
    __shared__ int lcnt[8], lbase[8];
    const int tok = blockIdx.x * 256 + threadIdx.x;
    if (threadIdx.x < 8) lcnt[threadIdx.x] = 0;
    __syncthreads();
    const unsigned pk = topk_idx[tok];
    int e[4], off[4]; float g[4];
#pragma unroll
    for (int k = 0; k < 4; ++k) {
        e[k] = (pk >> (8 * k)) & 255;
        g[k] = topk_gate[tok * 4 + k];
        off[k] = atomicAdd(&lcnt[e[k]], 1);
    }
    __syncthreads();
    if (threadIdx.x < 8) lbase[threadIdx.x] = atomicAdd(&gcount[threadIdx.x], lcnt[threadIdx.x]);
    __syncthreads();
#pragma unroll
    for (int k = 0; k < 4; ++k) {
        int pos = lbase[e[k]] + off[k];
        pair_tok[e[k] * T_ + pos]  = tok;
        pair_gate[e[k] * T_ + pos] = g[k];
    }
}

// ---------------------------------------------------------------------------
// Kernel 4: tile scan. meta[0]=ntiles; meta[1+e]=padded row base;
// desc at meta[32+t] = (e<<16)|local_mtile.
// Identity used by the chunked GEMMs: meta[1+e] + mloc*128 == t*128, i.e.
// the global padded h-row base of tile t is just t*128. Chunk c covers
// tiles [base, base+CT) and stores their h rows at (t-base)*128 in the
// reused chunk buffer.
// ---------------------------------------------------------------------------
__global__ void scan_kernel(const int* __restrict__ gcount, int* __restrict__ meta)
{
    const int t = threadIdx.x;
    if (t < 8) {
        int tiles_before = 0, rows_before = 0;
        for (int i = 0; i < t; ++i) {
            int c = gcount[i];
            int nt = (c + 127) >> 7;
            tiles_before += nt; rows_before += nt << 7;
        }
        int c  = gcount[t];
        int nt = (c + 127) >> 7;
        meta[1 + t] = rows_before;
        for (int i = 0; i < nt; ++i) meta[32 + tiles_before + i] = (t << 16) | i;
        if (t == 7) meta[0] = tiles_before + nt;
    }
}

// ---------------------------------------------------------------------------
// Grouped GEMM1 (chunk of tiles, all experts mixed):
// h[(tile-base)*128 ...] = gelu(xn[gather] @ w1t^T + b1)
// ---------------------------------------------------------------------------
__global__ __launch_bounds__(256) void gemm1_grouped(
    const u16* __restrict__ xn, const u16* __restrict__ w1t,
    const float* __restrict__ b1, const int* __restrict__ pair_tok,
    const int* __restrict__ gcount, const int* __restrict__ meta,
    u16* __restrict__ h, int chunk_base)
{
    const int tile = chunk_base + blockIdx.y;
    if (tile >= meta[0]) return;
    const int dsc  = meta[32 + tile];
    const int e    = dsc >> 16;
    const int mloc = dsc & 0xffff;
    const int nt   = blockIdx.x;
    const int* ptok = pair_tok + e * T_;
    const u16* w1t_e = w1t + (size_t)e * D_ * H_;
    const float* b1_e = b1 + (size_t)e * H_;
    u16* hbase = h + (size_t)blockIdx.y * 128 * H_;   // chunk-local rows

    __shared__ __align__(16) u16 As[128 * 32];
    __shared__ __align__(16) u16 Bs[128 * 32];

    const int tid  = threadIdx.x;
    const int lane = tid & 63;
    const int wave = tid >> 6;
    const int rs0 = tid >> 2;
    const int kg0 = (tid & 3) ^ ((rs0 >> 1) & 3);

    const int tokA0 = ptok[mloc * 128 + rs0];
    const int tokA1 = ptok[mloc * 128 + 64 + rs0];
    const u16* gA0 = xn + (size_t)tokA0 * D_ + kg0 * 8;
    const u16* gA1 = xn + (size_t)tokA1 * D_ + kg0 * 8;
    const u16* gB0 = w1t_e + (size_t)(nt * 128 + rs0) * D_ + kg0 * 8;
    const u16* gB1 = w1t_e + (size_t)(nt * 128 + 64 + rs0) * D_ + kg0 * 8;

    u16* AsW = As + wave * 512;
    u16* BsW = Bs + wave * 512;

    const int wm = (wave >> 1) * 64;
    const int wn = (wave & 1) * 64;
    const int fr = lane & 15;
    const int swz = (((lane >> 4) ^ ((fr >> 1) & 3))) * 8;

    f32x4 acc[4][4];
#pragma unroll
    for (int i = 0; i < 4; ++i)
#pragma unroll
        for (int j = 0; j < 4; ++j) acc[i][j] = (f32x4)0.0f;

    for (int kk = 0; kk < D_ / 32; ++kk) {
        gload_lds16(gA0, AsW);
        gload_lds16(gA1, AsW + 2048);
        gload_lds16(gB0, BsW);
        gload_lds16(gB1, BsW + 2048);
        gA0 += 32; gA1 += 32; gB0 += 32; gB1 += 32;
        __syncthreads();
        short8 a[4], b[4];
#pragma unroll
        for (int i = 0; i < 4; ++i) a[i] = *(const short8*)(As + (wm + i * 16 + fr) * 32 + swz);
#pragma unroll
        for (int i = 0; i < 4; ++i) b[i] = *(const short8*)(Bs + (wn + i * 16 + fr) * 32 + swz);
#pragma unroll
        for (int i = 0; i < 4; ++i)
#pragma unroll
            for (int j = 0; j < 4; ++j)
                acc[i][j] = __builtin_amdgcn_mfma_f32_16x16x32_bf16(a[i], b[j], acc[i][j], 0, 0, 0);
        __syncthreads();
    }

    const int cq = lane >> 4;
    const int cc = lane & 15;
#pragma unroll
    for (int j = 0; j < 4; ++j) {
        const int gcol = nt * 128 + wn + j * 16 + cc;
        const float bias = b1_e[gcol];
#pragma unroll
        for (int i = 0; i < 4; ++i) {
            const int lr0 = wm + i * 16 + cq * 4;
#pragma unroll
            for (int r = 0; r < 4; ++r) {
                float vv = gelu_exact(acc[i][j][r] + bias);
                hbase[(size_t)(lr0 + r) * H_ + gcol] = f2bf(vv);
            }
        }
    }
}

// Grouped GEMM2 (chunk): y[tok] += gate*(h @ w2t^T + b2), atomicAdd
// (cross-expert concurrent writers to the same token row).
__global__ __launch_bounds__(256) void gemm2_grouped(
    const u16* __restrict__ h, const u16* __restrict__ w2t,
    const float* __restrict__ b2, const int* __restrict__ pair_tok,
    const float* __restrict__ pair_gate, const int* __restrict__ gcount,
    const int* __restrict__ meta, float* __restrict__ y, int chunk_base)
{
    const int tile = chunk_base + blockIdx.y;
    if (tile >= meta[0]) return;
    const int dsc  = meta[32 + tile];
    const int e    = dsc >> 16;
    const int mloc = dsc & 0xffff;
    const int count = gcount[e];
    const int nt   = blockIdx.x;
    const int* ptok = pair_tok + e * T_;
    const float* pgate = pair_gate + e * T_;
    const u16* w2t_e = w2t + (size_t)e * OUT_ * H_;
    const float* b2_e = b2 + (size_t)e * OUT_;
    const u16* hbase = h + (size_t)blockIdx.y * 128 * H_;   // chunk-local rows

    __shared__ __align__(16) u16 As[128 * 32];
    __shared__ __align__(16) u16 Bs[128 * 32];

    const int tid  = threadIdx.x;
    const int lane = tid & 63;
    const int wave = tid >> 6;
    const int rs0 = tid >> 2;
    const int kg0 = (tid & 3) ^ ((rs0 >> 1) & 3);

    const u16* gA0 = hbase + (size_t)rs0 * H_ + kg0 * 8;
    const u16* gA1 = hbase + (size_t)(64 + rs0) * H_ + kg0 * 8;
    const u16* gB0 = w2t_e + (size_t)(nt * 128 + rs0) * H_ + kg0 * 8;
    const u16* gB1 = w2t_e + (size_t)(nt * 128 + 64 + rs0) * H_ + kg0 * 8;

    u16* AsW = As + wave * 512;
    u16* BsW = Bs + wave * 512;

    const int wm = (wave >> 1) * 64;
    const int wn = (wave & 1) * 64;
    const int fr = lane & 15;
    const int swz = (((lane >> 4) ^ ((fr >> 1) & 3))) * 8;

    f32x4 acc[4][4];
#pragma unroll
    for (int i = 0; i < 4; ++i)
#pragma unroll
        for (int j = 0; j < 4; ++j) acc[i][j] = (f32x4)0.0f;

    for (int kk = 0; kk < H_ / 32; ++kk) {
        gload_lds16(gA0, AsW);
        gload_lds16(gA1, AsW + 2048);
        gload_lds16(gB0, BsW);
        gload_lds16(gB1, BsW + 2048);
        gA0 += 32; gA1 += 32; gB0 += 32; gB1 += 32;
        __syncthreads();
        short8 a[4], b[4];
#pragma unroll
        for (int i = 0; i < 4; ++i) a[i] = *(const short8*)(As + (wm + i * 16 + fr) * 32 + swz);
#pragma unroll
        for (int i = 0; i < 4; ++i) b[i] = *(const short8*)(Bs + (wn + i * 16 + fr) * 32 + swz);
#pragma unroll
        for (int i = 0; i < 4; ++i)
#pragma unroll
            for (int j = 0; j < 4; ++j)
                acc[i][j] = __builtin_amdgcn_mfma_f32_16x16x32_bf16(a[i], b[j], acc[i][j], 0, 0, 0);
        __syncthreads();
    }

    const int cq = lane >> 4;
    const int cc = lane & 15;
#pragma unroll
    for (int i = 0; i < 4; ++i) {
#pragma unroll
        for (int r = 0; r < 4; ++r) {
            const int lrow = wm + i * 16 + cq * 4 + r;
            if (mloc * 128 + lrow < count) {
                const int tok = ptok[mloc * 128 + lrow];
                const float g = pgate[mloc * 128 + lrow];
                float* yrow = y + (size_t)tok * OUT_;
#pragma unroll
                for (int j = 0; j < 4; ++j) {
                    const int gcol = nt * 128 + wn + j * 16 + cc;
                    atomicAdd(&yrow[gcol], g * (acc[i][j][r] + b2_e[gcol]));
                }
            }
        }
    }
}

// ---------------------------------------------------------------------------
// Fallback per-expert kernels (used only if ws can't hold even a small chunk)
// ---------------------------------------------------------------------------
__global__ __launch_bounds__(256) void gemm1_kernel(
    const u16* __restrict__ xn, const u16* __restrict__ w1t_e,
    const float* __restrict__ b1_e, const int* __restrict__ ptok,
    const int* __restrict__ pcount, u16* __restrict__ h)
{
    const int count = *pcount;
    const int mt = blockIdx.y;
    if (mt * 128 >= count) return;
    const int nt = blockIdx.x;
    __shared__ __align__(16) u16 As[128 * 32];
    __shared__ __align__(16) u16 Bs[128 * 32];
    const int tid  = threadIdx.x;
    const int lane = tid & 63;
    const int wave = tid >> 6;
    const int rs0 = tid >> 2;
    const int kg0 = (tid & 3) ^ ((rs0 >> 1) & 3);
    const int tokA0 = ptok[mt * 128 + rs0];
    const int tokA1 = ptok[mt * 128 + 64 + rs0];
    const u16* gA0 = xn + (size_t)tokA0 * D_ + kg0 * 8;
    const u16* gA1 = xn + (size_t)tokA1 * D_ + kg0 * 8;
    const u16* gB0 = w1t_e + (size_t)(nt * 128 + rs0) * D_ + kg0 * 8;
    const u16* gB1 = w1t_e + (size_t)(nt * 128 + 64 + rs0) * D_ + kg0 * 8;
    u16* AsW = As + wave * 512;
    u16* BsW = Bs + wave * 512;
    const int wm = (wave >> 1) * 64;
    const int wn = (wave & 1) * 64;
    const int fr = lane & 15;
    const int swz = (((lane >> 4) ^ ((fr >> 1) & 3))) * 8;
    f32x4 acc[4][4];
#pragma unroll
    for (int i = 0; i < 4; ++i)
#pragma unroll
        for (int j = 0; j < 4; ++j) acc[i][j] = (f32x4)0.0f;
    for (int kk = 0; kk < D_ / 32; ++kk) {
        gload_lds16(gA0, AsW); gload_lds16(gA1, AsW + 2048);
        gload_lds16(gB0, BsW); gload_lds16(gB1, BsW + 2048);
        gA0 += 32; gA1 += 32; gB0 += 32; gB1 += 32;
        __syncthreads();
        short8 a[4], b[4];
#pragma unroll
        for (int i = 0; i < 4; ++i) a[i] = *(const short8*)(As + (wm + i * 16 + fr) * 32 + swz);
#pragma unroll
        for (int i = 0; i < 4; ++i) b[i] = *(const short8*)(Bs + (wn + i * 16 + fr) * 32 + swz);
#pragma unroll
        for (int i = 0; i < 4; ++i)
#pragma unroll
            for (int j = 0; j < 4; ++j)
                acc[i][j] = __builtin_amdgcn_mfma_f32_16x16x32_bf16(a[i], b[j], acc[i][j], 0, 0, 0);
        __syncthreads();
    }
    const int cq = lane >> 4;
    const int cc = lane & 15;
#pragma unroll
    for (int j = 0; j < 4; ++j) {
        const int gcol = nt * 128 + wn + j * 16 + cc;
        const float bias = b1_e[gcol];
#pragma unroll
        for (int i = 0; i < 4; ++i) {
            const int grow0 = mt * 128 + wm + i * 16 + cq * 4;
#pragma unroll
            for (int r = 0; r < 4; ++r) {
                float vv = gelu_exact(acc[i][j][r] + bias);
                h[(size_t)(grow0 + r) * H_ + gcol] = f2bf(vv);
            }
        }
    }
}

__global__ __launch_bounds__(256) void gemm2_kernel(
    const u16* __restrict__ h, const u16* __restrict__ w2t_e,
    const float* __restrict__ b2_e, const int* __restrict__ ptok,
    const float* __restrict__ pgate, const int* __restrict__ pcount,
    float* __restrict__ y)
{
    const int count = *pcount;
    const int mt = blockIdx.y;
    if (mt * 128 >= count) return;
    const int nt = blockIdx.x;
    __shared__ __align__(16) u16 As[128 * 32];
    __shared__ __align__(16) u16 Bs[128 * 32];
    const int tid  = threadIdx.x;
    const int lane = tid & 63;
    const int wave = tid >> 6;
    const int rs0 = tid >> 2;
    const int kg0 = (tid & 3) ^ ((rs0 >> 1) & 3);
    const u16* gA0 = h + (size_t)(mt * 128 + rs0) * H_ + kg0 * 8;
    const u16* gA1 = h + (size_t)(mt * 128 + 64 + rs0) * H_ + kg0 * 8;
    const u16* gB0 = w2t_e + (size_t)(nt * 128 + rs0) * H_ + kg0 * 8;
    const u16* gB1 = w2t_e + (size_t)(nt * 128 + 64 + rs0) * H_ + kg0 * 8;
    u16* AsW = As + wave * 512;
    u16* BsW = Bs + wave * 512;
    const int wm = (wave >> 1) * 64;
    const int wn = (wave & 1) * 64;
    const int fr = lane & 15;
    const int swz = (((lane >> 4) ^ ((fr >> 1) & 3))) * 8;
    f32x4 acc[4][4];
#pragma unroll
    for (int i = 0; i < 4; ++i)
#pragma unroll
        for (int j = 0; j < 4; ++j) acc[i][j] = (f32x4)0.0f;
    for (int kk = 0; kk < H_ / 32; ++kk) {
        gload_lds16(gA0, AsW); gload_lds16(gA1, AsW + 2048);
        gload_lds16(gB0, BsW); gload_lds16(gB1, BsW + 2048);
        gA0 += 32; gA1 += 32; gB0 += 32; gB1 += 32;
        __syncthreads();
        short8 a[4], b[4];
#pragma unroll
        for (int i = 0; i < 4; ++i) a[i] = *(const short8*)(As + (wm + i * 16 + fr) * 32 + swz);
#pragma unroll
        for (int i = 0; i < 4; ++i) b[i] = *(const short8*)(Bs + (wn + i * 16 + fr) * 32 + swz);
#pragma unroll
        for (int i = 0; i < 4; ++i)
#pragma unroll
            for (int j = 0; j < 4; ++j)
                acc[i][j] = __builtin_amdgcn_mfma_f32_16x16x32_bf16(a[i], b[j], acc[i][j], 0, 0, 0);
        __syncthreads();
    }
    const int cq = lane >> 4;
    const int cc = lane & 15;
#pragma unroll
    for (int i = 0; i < 4; ++i) {
#pragma unroll
        for (int r = 0; r < 4; ++r) {
            const int irow = mt * 128 + wm + i * 16 + cq * 4 + r;
            if (irow < count) {
                const int tok = ptok[irow];
                const float g = pgate[irow];
                float* yrow = y + (size_t)tok * OUT_;
#pragma unroll
                for (int j = 0; j < 4; ++j) {
                    const int gcol = nt * 128 + wn + j * 16 + cc;
                    yrow[gcol] += g * (acc[i][j][r] + b2_e[gcol]);
                }
            }
        }
    }
}

// ---------------------------------------------------------------------------
extern "C" void kernel_launch(void* const* d_in, const int* in_sizes, int n_in,
                              void* d_out, int out_size, void* d_ws, size_t ws_size,
                              hipStream_t stream)
{
    const float* x     = (const float*)d_in[0];
    const float* gamma = (const float*)d_in[1];
    const float* beta  = (const float*)d_in[2];
    const float* rw    = (const float*)d_in[3];
    const float* rb    = (const float*)d_in[4];
    const float* w1    = (const float*)d_in[5];
    const float* b1    = (const float*)d_in[6];
    const float* w2    = (const float*)d_in[7];
    const float* b2    = (const float*)d_in[8];
    float* y = (float*)d_out;

    char* ws = (char*)d_ws;
    const size_t xn_off   = 0;                         // 64 MB
    const size_t w1t_off  = 67108864;                  // 32 MB
    const size_t w2t_off  = 100663296;                 // 32 MB
    const size_t ptok_off = 134217728;                 // 1 MB
    const size_t pgat_off = 135266304;                 // 1 MB
    const size_t tidx_off = 136314880;                 // 128 KB
    const size_t tgat_off = 136445952;                 // 512 KB
    const size_t meta_off = 136970240;                 // 8 KB (incl desc)
    const size_t gcnt_off = 136978432;                 // 32 B
    const size_t h_off    = 137363456;                 // h chunk buffer

    u16*      xn        = (u16*)(ws + xn_off);
    u16*      w1t       = (u16*)(ws + w1t_off);
    u16*      w2t       = (u16*)(ws + w2t_off);
    int*      pair_tok  = (int*)(ws + ptok_off);
    float*    pair_gate = (float*)(ws + pgat_off);
    unsigned* topk_idx  = (unsigned*)(ws + tidx_off);
    float*    topk_gate = (float*)(ws + tgat_off);
    int*      meta      = (int*)(ws + meta_off);
    int*      gcount    = (int*)(ws + gcnt_off);
    u16*      h         = (u16*)(ws + h_off);

    hipMemsetAsync(gcount, 0, 32, stream);
    hipMemsetAsync(pair_tok, 0, (size_t)E_ * T_ * 4, stream);
    hipMemsetAsync(d_out, 0, (size_t)T_ * OUT_ * 4, stream);

    ln_router_kernel<<<T_ / 4, 256, 0, stream>>>(x, gamma, beta, rw, rb, xn, topk_idx, topk_gate);
    transpose_cvt_kernel<<<32768, 256, 0, stream>>>(w1, w2, w1t, w2t);
    pair_build_kernel<<<T_ / 256, 256, 0, stream>>>(topk_idx, topk_gate, pair_tok, pair_gate, gcount);

    // Chunked grouped path: h chunk holds CT tiles (512 KB/tile). With the
    // ~271 MB workspace the fallback previously used, CT ~= 255 -> 5 chunk
    // pairs, each with 2-4k active blocks (vs 16 serial starving launches).
    const size_t tile_bytes = (size_t)128 * H_ * 2;    // 512 KB / tile
    size_t avail = (ws_size > h_off) ? (ws_size - h_off) : 0;
    int CT = (int)(avail / tile_bytes);
    if (CT > MAXTILES_) CT = MAXTILES_;

    if (CT >= 64) {
        scan_kernel<<<1, 64, 0, stream>>>(gcount, meta);
        for (int base = 0; base < MAXTILES_; base += CT) {
            const int tiles = (MAXTILES_ - base < CT) ? (MAXTILES_ - base) : CT;
            gemm1_grouped<<<dim3(H_ / 128, tiles), 256, 0, stream>>>(
                xn, w1t, b1, pair_tok, gcount, meta, h, base);
            gemm2_grouped<<<dim3(OUT_ / 128, tiles), 256, 0, stream>>>(
                h, w2t, b2, pair_tok, pair_gate, gcount, meta, y, base);
        }
    } else {
        for (int e = 0; e < E_; ++e) {
            gemm1_kernel<<<dim3(H_ / 128, T_ / 128), 256, 0, stream>>>(
                xn, w1t + (size_t)e * H_ * D_, b1 + (size_t)e * H_,
                pair_tok + (size_t)e * T_, gcount + e, h);
            gemm2_kernel<<<dim3(OUT_ / 128, T_ / 128), 256, 0, stream>>>(
                h, w2t + (size_t)e * OUT_ * H_, b2 + (size_t)e * OUT_,
                pair_tok + (size_t)e * T_, pair_gate + (size_t)e * T_, gcount + e, y);
        }
    }
}

// Round 2
// 2268.570 us; speedup vs baseline: 1.0834x; 1.0834x over previous
//
#include <hip/hip_runtime.h>
#include <hip/hip_bf16.h>
#include <math.h>

typedef unsigned short u16;
typedef __attribute__((ext_vector_type(8))) short short8;
typedef __attribute__((ext_vector_type(4))) float f32x4;
typedef __attribute__((ext_vector_type(4))) unsigned short u16x4;

constexpr int T_   = 32768;
constexpr int D_   = 1024;
constexpr int H_   = 2048;
constexpr int OUT_ = 1024;
constexpr int E_   = 8;
constexpr int MAXTILES_ = 1040;

__device__ __forceinline__ u16 f2bf(float f) {
    unsigned u = __float_as_uint(f);
    u += 0x7FFFu + ((u >> 16) & 1u);
    return (u16)(u >> 16);
}

__device__ __forceinline__ void gload_lds16(const u16* g, u16* l) {
    __builtin_amdgcn_global_load_lds(
        (const __attribute__((address_space(1))) unsigned int*)g,
        (__attribute__((address_space(3))) unsigned int*)l, 16, 0, 0);
}

__device__ __forceinline__ float gelu_exact(float v) {
    return 0.5f * v * (1.0f + erff(v * 0.70710678118654752f));
}

// ---------------------------------------------------------------------------
// Kernel 1: fused LayerNorm + router. Block = 4 rows (1/wave).
// ---------------------------------------------------------------------------
__global__ __launch_bounds__(256) void ln_router_kernel(
    const float* __restrict__ x, const float* __restrict__ gamma,
    const float* __restrict__ beta, const float* __restrict__ rw,
    const float* __restrict__ rb, u16* __restrict__ xn,
    unsigned* __restrict__ topk_idx, float* __restrict__ topk_gate)
{
    __shared__ float xn_lds[4 * 1024];     // 16 KB
    __shared__ float rwT[8 * 1024];        // 32 KB
    __shared__ float plog[4 * 32 * 8];     // 4 KB  [row][slot][e]

    const int tid  = threadIdx.x;
    const int lane = tid & 63;
    const int wave = tid >> 6;
    const int row  = blockIdx.x * 4 + wave;
    const float* xr = x + (size_t)row * D_;

    // stage rw -> rwT (transposed), coalesced global float4 reads
#pragma unroll
    for (int it = 0; it < 8; ++it) {
        const int f0 = it * 1024 + tid * 4;
        float4 v4 = *(const float4*)(rw + f0);
        const int d  = f0 >> 3;
        const int e0 = (tid & 1) * 4;
        rwT[(e0 + 0) * 1024 + d] = v4.x;
        rwT[(e0 + 1) * 1024 + d] = v4.y;
        rwT[(e0 + 2) * 1024 + d] = v4.z;
        rwT[(e0 + 3) * 1024 + d] = v4.w;
    }

    // Phase A: LN
    float v[16];
#pragma unroll
    for (int j = 0; j < 4; ++j) {
        float4 t = *(const float4*)(xr + (j * 64 + lane) * 4);
        v[j*4+0] = t.x; v[j*4+1] = t.y; v[j*4+2] = t.z; v[j*4+3] = t.w;
    }
    float s = 0.f, ss = 0.f;
#pragma unroll
    for (int i = 0; i < 16; ++i) { s += v[i]; ss += v[i] * v[i]; }
#pragma unroll
    for (int st = 32; st > 0; st >>= 1) { s += __shfl_xor(s, st); ss += __shfl_xor(ss, st); }
    const float mu   = s * (1.0f / 1024.0f);
    const float var  = ss * (1.0f / 1024.0f) - mu * mu;
    const float rstd = rsqrtf(var + 1e-5f);

#pragma unroll
    for (int j = 0; j < 4; ++j) {
        const int d0 = (j * 64 + lane) * 4;
        float4 g4 = *(const float4*)(gamma + d0);
        float4 b4 = *(const float4*)(beta + d0);
        f32x4 xnv;
        xnv[0] = (v[j*4+0] - mu) * rstd * g4.x + b4.x;
        xnv[1] = (v[j*4+1] - mu) * rstd * g4.y + b4.y;
        xnv[2] = (v[j*4+2] - mu) * rstd * g4.z + b4.z;
        xnv[3] = (v[j*4+3] - mu) * rstd * g4.w + b4.w;
        *(f32x4*)(xn_lds + wave * 1024 + d0) = xnv;
        u16x4 pk;
        pk.x = f2bf(xnv[0]); pk.y = f2bf(xnv[1]);
        pk.z = f2bf(xnv[2]); pk.w = f2bf(xnv[3]);
        *(u16x4*)(xn + (size_t)row * D_ + d0) = pk;
    }
    __syncthreads();

    // Phase B: lane -> (e = lane>>3, dseg = lane&7)
    const int e    = lane >> 3;
    const int dseg = lane & 7;
    float part[4] = {0.f, 0.f, 0.f, 0.f};
#pragma unroll
    for (int ii = 0; ii < 8; ++ii) {
        const int q = dseg + (wave * 8 + ii) * 8;      // quad index 0..255
        f32x4 rw4 = *(const f32x4*)(rwT + e * 1024 + q * 4);
#pragma unroll
        for (int r = 0; r < 4; ++r) {
            f32x4 x4 = *(const f32x4*)(xn_lds + r * 1024 + q * 4);
            part[r] += x4[0]*rw4[0] + x4[1]*rw4[1] + x4[2]*rw4[2] + x4[3]*rw4[3];
        }
    }
#pragma unroll
    for (int r = 0; r < 4; ++r)
        plog[(r * 32 + wave * 8 + dseg) * 8 + e] = part[r];
    __syncthreads();

    const int rr = wave;
    const int ee = (lane >> 3) & 7;
    const int s8 = lane & 7;
    float val = plog[(rr * 32 + s8) * 8 + ee] + plog[(rr * 32 + s8 + 8) * 8 + ee]
              + plog[(rr * 32 + s8 + 16) * 8 + ee] + plog[(rr * 32 + s8 + 24) * 8 + ee];
    val += __shfl_xor(val, 1);
    val += __shfl_xor(val, 2);
    val += __shfl_xor(val, 4);
    val += rb[ee];

    float vv[8];
#pragma unroll
    for (int k = 0; k < 8; ++k) vv[k] = __shfl(val, k * 8);

    if (lane == 0) {
        unsigned used = 0, pack = 0;
        float tv[4];
#pragma unroll
        for (int k = 0; k < 4; ++k) {
            float best = -3.4e38f; int bi = 0;
#pragma unroll
            for (int q = 0; q < 8; ++q)
                if (!((used >> q) & 1) && vv[q] > best) { best = vv[q]; bi = q; }
            used |= 1u << bi; tv[k] = best; pack |= (unsigned)bi << (8 * k);
        }
        float ex[4], sum = 0.f;
#pragma unroll
        for (int k = 0; k < 4; ++k) { ex[k] = expf(tv[k] - tv[0]); sum += ex[k]; }
        const float inv = 1.0f / sum;
        topk_idx[row] = pack;
#pragma unroll
        for (int k = 0; k < 4; ++k) topk_gate[row * 4 + k] = ex[k] * inv;
    }
}

// ---------------------------------------------------------------------------
// Kernel 2: transpose+convert weights to bf16 B^T (k-contiguous) layout.
// ---------------------------------------------------------------------------
__global__ __launch_bounds__(256) void transpose_cvt_kernel(
    const float* __restrict__ w1, const float* __restrict__ w2,
    u16* __restrict__ w1t, u16* __restrict__ w2t)
{
    __shared__ float lds[32][33];
    int t = blockIdx.x;
    const float* src; u16* dst; int R, C, rt, ct;
    if (t < 16384) {
        int e = t >> 11, loc = t & 2047;
        rt = loc >> 6; ct = loc & 63;
        src = w1 + (size_t)e * D_ * H_; dst = w1t + (size_t)e * D_ * H_;
        R = D_; C = H_;
    } else {
        t -= 16384;
        int e = t >> 11, loc = t & 2047;
        rt = loc >> 5; ct = loc & 31;
        src = w2 + (size_t)e * H_ * OUT_; dst = w2t + (size_t)e * H_ * OUT_;
        R = H_; C = OUT_;
    }
    const int r  = threadIdx.x >> 3;
    const int c4 = (threadIdx.x & 7) * 4;
    float4 val = *(const float4*)(src + (size_t)(rt * 32 + r) * C + ct * 32 + c4);
    lds[r][c4+0] = val.x; lds[r][c4+1] = val.y; lds[r][c4+2] = val.z; lds[r][c4+3] = val.w;
    __syncthreads();
    const int cc = threadIdx.x >> 3;
    const int r4 = (threadIdx.x & 7) * 4;
    u16x4 o;
    o.x = f2bf(lds[r4+0][cc]); o.y = f2bf(lds[r4+1][cc]);
    o.z = f2bf(lds[r4+2][cc]); o.w = f2bf(lds[r4+3][cc]);
    *(u16x4*)(dst + (size_t)(ct * 32 + cc) * R + rt * 32 + r4) = o;
}

// ---------------------------------------------------------------------------
// Kernel 3: build per-expert compacted (token, gate) pair lists.
// ---------------------------------------------------------------------------
__global__ __launch_bounds__(256) void pair_build_kernel(
    const unsigned* __restrict__ topk_idx, const float* __restrict__ topk_gate,
    int* __restrict__ pair_tok, float* __restrict__ pair_gate, int* __restrict__ gcount)
{
    __shared__ int lcnt[8], lbase[8];
    const int tok = blockIdx.x * 256 + threadIdx.x;
    if (threadIdx.x < 8) lcnt[threadIdx.x] = 0;
    __syncthreads();
    const unsigned pk = topk_idx[tok];
    int e[4], off[4]; float g[4];
#pragma unroll
    for (int k = 0; k < 4; ++k) {
        e[k] = (pk >> (8 * k)) & 255;
        g[k] = topk_gate[tok * 4 + k];
        off[k] = atomicAdd(&lcnt[e[k]], 1);
    }
    __syncthreads();
    if (threadIdx.x < 8) lbase[threadIdx.x] = atomicAdd(&gcount[threadIdx.x], lcnt[threadIdx.x]);
    __syncthreads();
#pragma unroll
    for (int k = 0; k < 4; ++k) {
        int pos = lbase[e[k]] + off[k];
        pair_tok[e[k] * T_ + pos]  = tok;
        pair_gate[e[k] * T_ + pos] = g[k];
    }
}

// ---------------------------------------------------------------------------
// Kernel 4: tile scan. meta[0]=ntiles; meta[1+e]=padded row base;
// desc at meta[32+t] = (e<<16)|local_mtile.
// ---------------------------------------------------------------------------
__global__ void scan_kernel(const int* __restrict__ gcount, int* __restrict__ meta)
{
    const int t = threadIdx.x;
    if (t < 8) {
        int tiles_before = 0, rows_before = 0;
        for (int i = 0; i < t; ++i) {
            int c = gcount[i];
            int nt = (c + 127) >> 7;
            tiles_before += nt; rows_before += nt << 7;
        }
        int c  = gcount[t];
        int nt = (c + 127) >> 7;
        meta[1 + t] = rows_before;
        for (int i = 0; i < nt; ++i) meta[32 + tiles_before + i] = (t << 16) | i;
        if (t == 7) meta[0] = tiles_before + nt;
    }
}

// ---------------------------------------------------------------------------
// Grouped GEMM1 (chunk of tiles, all experts mixed), 1-D swizzled grid.
// Flat id f = q*128 + nt*8 + x  ->  tloc = q*8 + x (chunk-local tile),
// nt in [0,16). All 16 co-A-panel blocks of a tile share hw-XCD (f%8 = x)
// and sit within one 128-id dispatch window (co-resident) -> A panel is
// fetched into one XCD L2 once. Requires chunk tile count % 8 == 0.
// h[(tloc)*128 ...] = gelu(xn[gather] @ w1t^T + b1)
// ---------------------------------------------------------------------------
__global__ __launch_bounds__(256) void gemm1_grouped(
    const u16* __restrict__ xn, const u16* __restrict__ w1t,
    const float* __restrict__ b1, const int* __restrict__ pair_tok,
    const int* __restrict__ gcount, const int* __restrict__ meta,
    u16* __restrict__ h, int chunk_base)
{
    const int f    = blockIdx.x;
    const int tloc = (f >> 7) * 8 + (f & 7);
    const int nt   = (f >> 3) & 15;
    const int tile = chunk_base + tloc;
    if (tile >= meta[0]) return;
    const int dsc  = meta[32 + tile];
    const int e    = dsc >> 16;
    const int mloc = dsc & 0xffff;
    const int* ptok = pair_tok + e * T_;
    const u16* w1t_e = w1t + (size_t)e * D_ * H_;
    const float* b1_e = b1 + (size_t)e * H_;
    u16* hbase = h + (size_t)tloc * 128 * H_;   // chunk-local rows

    __shared__ __align__(16) u16 As[128 * 32];
    __shared__ __align__(16) u16 Bs[128 * 32];

    const int tid  = threadIdx.x;
    const int lane = tid & 63;
    const int wave = tid >> 6;
    const int rs0 = tid >> 2;
    const int kg0 = (tid & 3) ^ ((rs0 >> 1) & 3);

    const int tokA0 = ptok[mloc * 128 + rs0];
    const int tokA1 = ptok[mloc * 128 + 64 + rs0];
    const u16* gA0 = xn + (size_t)tokA0 * D_ + kg0 * 8;
    const u16* gA1 = xn + (size_t)tokA1 * D_ + kg0 * 8;
    const u16* gB0 = w1t_e + (size_t)(nt * 128 + rs0) * D_ + kg0 * 8;
    const u16* gB1 = w1t_e + (size_t)(nt * 128 + 64 + rs0) * D_ + kg0 * 8;

    u16* AsW = As + wave * 512;
    u16* BsW = Bs + wave * 512;

    const int wm = (wave >> 1) * 64;
    const int wn = (wave & 1) * 64;
    const int fr = lane & 15;
    const int swz = (((lane >> 4) ^ ((fr >> 1) & 3))) * 8;

    f32x4 acc[4][4];
#pragma unroll
    for (int i = 0; i < 4; ++i)
#pragma unroll
        for (int j = 0; j < 4; ++j) acc[i][j] = (f32x4)0.0f;

    for (int kk = 0; kk < D_ / 32; ++kk) {
        gload_lds16(gA0, AsW);
        gload_lds16(gA1, AsW + 2048);
        gload_lds16(gB0, BsW);
        gload_lds16(gB1, BsW + 2048);
        gA0 += 32; gA1 += 32; gB0 += 32; gB1 += 32;
        __syncthreads();
        short8 a[4], b[4];
#pragma unroll
        for (int i = 0; i < 4; ++i) a[i] = *(const short8*)(As + (wm + i * 16 + fr) * 32 + swz);
#pragma unroll
        for (int i = 0; i < 4; ++i) b[i] = *(const short8*)(Bs + (wn + i * 16 + fr) * 32 + swz);
#pragma unroll
        for (int i = 0; i < 4; ++i)
#pragma unroll
            for (int j = 0; j < 4; ++j)
                acc[i][j] = __builtin_amdgcn_mfma_f32_16x16x32_bf16(a[i], b[j], acc[i][j], 0, 0, 0);
        __syncthreads();
    }

    const int cq = lane >> 4;
    const int cc = lane & 15;
#pragma unroll
    for (int j = 0; j < 4; ++j) {
        const int gcol = nt * 128 + wn + j * 16 + cc;
        const float bias = b1_e[gcol];
#pragma unroll
        for (int i = 0; i < 4; ++i) {
            const int lr0 = wm + i * 16 + cq * 4;
#pragma unroll
            for (int r = 0; r < 4; ++r) {
                float vv = gelu_exact(acc[i][j][r] + bias);
                hbase[(size_t)(lr0 + r) * H_ + gcol] = f2bf(vv);
            }
        }
    }
}

// Grouped GEMM2 (chunk, 1-D swizzled grid, NT=8):
// f = q*64 + nt*8 + x -> tloc = q*8 + x, nt in [0,8). Same-XCD h panels.
// y[tok] += gate*(h @ w2t^T + b2), atomicAdd.
__global__ __launch_bounds__(256) void gemm2_grouped(
    const u16* __restrict__ h, const u16* __restrict__ w2t,
    const float* __restrict__ b2, const int* __restrict__ pair_tok,
    const float* __restrict__ pair_gate, const int* __restrict__ gcount,
    const int* __restrict__ meta, float* __restrict__ y, int chunk_base)
{
    const int f    = blockIdx.x;
    const int tloc = (f >> 6) * 8 + (f & 7);
    const int nt   = (f >> 3) & 7;
    const int tile = chunk_base + tloc;
    if (tile >= meta[0]) return;
    const int dsc  = meta[32 + tile];
    const int e    = dsc >> 16;
    const int mloc = dsc & 0xffff;
    const int count = gcount[e];
    const int* ptok = pair_tok + e * T_;
    const float* pgate = pair_gate + e * T_;
    const u16* w2t_e = w2t + (size_t)e * OUT_ * H_;
    const float* b2_e = b2 + (size_t)e * OUT_;
    const u16* hbase = h + (size_t)tloc * 128 * H_;   // chunk-local rows

    __shared__ __align__(16) u16 As[128 * 32];
    __shared__ __align__(16) u16 Bs[128 * 32];

    const int tid  = threadIdx.x;
    const int lane = tid & 63;
    const int wave = tid >> 6;
    const int rs0 = tid >> 2;
    const int kg0 = (tid & 3) ^ ((rs0 >> 1) & 3);

    const u16* gA0 = hbase + (size_t)rs0 * H_ + kg0 * 8;
    const u16* gA1 = hbase + (size_t)(64 + rs0) * H_ + kg0 * 8;
    const u16* gB0 = w2t_e + (size_t)(nt * 128 + rs0) * H_ + kg0 * 8;
    const u16* gB1 = w2t_e + (size_t)(nt * 128 + 64 + rs0) * H_ + kg0 * 8;

    u16* AsW = As + wave * 512;
    u16* BsW = Bs + wave * 512;

    const int wm = (wave >> 1) * 64;
    const int wn = (wave & 1) * 64;
    const int fr = lane & 15;
    const int swz = (((lane >> 4) ^ ((fr >> 1) & 3))) * 8;

    f32x4 acc[4][4];
#pragma unroll
    for (int i = 0; i < 4; ++i)
#pragma unroll
        for (int j = 0; j < 4; ++j) acc[i][j] = (f32x4)0.0f;

    for (int kk = 0; kk < H_ / 32; ++kk) {
        gload_lds16(gA0, AsW);
        gload_lds16(gA1, AsW + 2048);
        gload_lds16(gB0, BsW);
        gload_lds16(gB1, BsW + 2048);
        gA0 += 32; gA1 += 32; gB0 += 32; gB1 += 32;
        __syncthreads();
        short8 a[4], b[4];
#pragma unroll
        for (int i = 0; i < 4; ++i) a[i] = *(const short8*)(As + (wm + i * 16 + fr) * 32 + swz);
#pragma unroll
        for (int i = 0; i < 4; ++i) b[i] = *(const short8*)(Bs + (wn + i * 16 + fr) * 32 + swz);
#pragma unroll
        for (int i = 0; i < 4; ++i)
#pragma unroll
            for (int j = 0; j < 4; ++j)
                acc[i][j] = __builtin_amdgcn_mfma_f32_16x16x32_bf16(a[i], b[j], acc[i][j], 0, 0, 0);
        __syncthreads();
    }

    const int cq = lane >> 4;
    const int cc = lane & 15;
    float b2v[4];
#pragma unroll
    for (int j = 0; j < 4; ++j) b2v[j] = b2_e[nt * 128 + wn + j * 16 + cc];
#pragma unroll
    for (int i = 0; i < 4; ++i) {
#pragma unroll
        for (int r = 0; r < 4; ++r) {
            const int lrow = wm + i * 16 + cq * 4 + r;
            if (mloc * 128 + lrow < count) {
                const int tok = ptok[mloc * 128 + lrow];
                const float g = pgate[mloc * 128 + lrow];
                float* yrow = y + (size_t)tok * OUT_;
#pragma unroll
                for (int j = 0; j < 4; ++j) {
                    const int gcol = nt * 128 + wn + j * 16 + cc;
                    atomicAdd(&yrow[gcol], g * (acc[i][j][r] + b2v[j]));
                }
            }
        }
    }
}

// ---------------------------------------------------------------------------
// Fallback per-expert kernels (used only if ws can't hold even a small chunk)
// ---------------------------------------------------------------------------
__global__ __launch_bounds__(256) void gemm1_kernel(
    const u16* __restrict__ xn, const u16* __restrict__ w1t_e,
    const float* __restrict__ b1_e, const int* __restrict__ ptok,
    const int* __restrict__ pcount, u16* __restrict__ h)
{
    const int count = *pcount;
    const int mt = blockIdx.y;
    if (mt * 128 >= count) return;
    const int nt = blockIdx.x;
    __shared__ __align__(16) u16 As[128 * 32];
    __shared__ __align__(16) u16 Bs[128 * 32];
    const int tid  = threadIdx.x;
    const int lane = tid & 63;
    const int wave = tid >> 6;
    const int rs0 = tid >> 2;
    const int kg0 = (tid & 3) ^ ((rs0 >> 1) & 3);
    const int tokA0 = ptok[mt * 128 + rs0];
    const int tokA1 = ptok[mt * 128 + 64 + rs0];
    const u16* gA0 = xn + (size_t)tokA0 * D_ + kg0 * 8;
    const u16* gA1 = xn + (size_t)tokA1 * D_ + kg0 * 8;
    const u16* gB0 = w1t_e + (size_t)(nt * 128 + rs0) * D_ + kg0 * 8;
    const u16* gB1 = w1t_e + (size_t)(nt * 128 + 64 + rs0) * D_ + kg0 * 8;
    u16* AsW = As + wave * 512;
    u16* BsW = Bs + wave * 512;
    const int wm = (wave >> 1) * 64;
    const int wn = (wave & 1) * 64;
    const int fr = lane & 15;
    const int swz = (((lane >> 4) ^ ((fr >> 1) & 3))) * 8;
    f32x4 acc[4][4];
#pragma unroll
    for (int i = 0; i < 4; ++i)
#pragma unroll
        for (int j = 0; j < 4; ++j) acc[i][j] = (f32x4)0.0f;
    for (int kk = 0; kk < D_ / 32; ++kk) {
        gload_lds16(gA0, AsW); gload_lds16(gA1, AsW + 2048);
        gload_lds16(gB0, BsW); gload_lds16(gB1, BsW + 2048);
        gA0 += 32; gA1 += 32; gB0 += 32; gB1 += 32;
        __syncthreads();
        short8 a[4], b[4];
#pragma unroll
        for (int i = 0; i < 4; ++i) a[i] = *(const short8*)(As + (wm + i * 16 + fr) * 32 + swz);
#pragma unroll
        for (int i = 0; i < 4; ++i) b[i] = *(const short8*)(Bs + (wn + i * 16 + fr) * 32 + swz);
#pragma unroll
        for (int i = 0; i < 4; ++i)
#pragma unroll
            for (int j = 0; j < 4; ++j)
                acc[i][j] = __builtin_amdgcn_mfma_f32_16x16x32_bf16(a[i], b[j], acc[i][j], 0, 0, 0);
        __syncthreads();
    }
    const int cq = lane >> 4;
    const int cc = lane & 15;
#pragma unroll
    for (int j = 0; j < 4; ++j) {
        const int gcol = nt * 128 + wn + j * 16 + cc;
        const float bias = b1_e[gcol];
#pragma unroll
        for (int i = 0; i < 4; ++i) {
            const int grow0 = mt * 128 + wm + i * 16 + cq * 4;
#pragma unroll
            for (int r = 0; r < 4; ++r) {
                float vv = gelu_exact(acc[i][j][r] + bias);
                h[(size_t)(grow0 + r) * H_ + gcol] = f2bf(vv);
            }
        }
    }
}

__global__ __launch_bounds__(256) void gemm2_kernel(
    const u16* __restrict__ h, const u16* __restrict__ w2t_e,
    const float* __restrict__ b2_e, const int* __restrict__ ptok,
    const float* __restrict__ pgate, const int* __restrict__ pcount,
    float* __restrict__ y)
{
    const int count = *pcount;
    const int mt = blockIdx.y;
    if (mt * 128 >= count) return;
    const int nt = blockIdx.x;
    __shared__ __align__(16) u16 As[128 * 32];
    __shared__ __align__(16) u16 Bs[128 * 32];
    const int tid  = threadIdx.x;
    const int lane = tid & 63;
    const int wave = tid >> 6;
    const int rs0 = tid >> 2;
    const int kg0 = (tid & 3) ^ ((rs0 >> 1) & 3);
    const u16* gA0 = h + (size_t)(mt * 128 + rs0) * H_ + kg0 * 8;
    const u16* gA1 = h + (size_t)(mt * 128 + 64 + rs0) * H_ + kg0 * 8;
    const u16* gB0 = w2t_e + (size_t)(nt * 128 + rs0) * H_ + kg0 * 8;
    const u16* gB1 = w2t_e + (size_t)(nt * 128 + 64 + rs0) * H_ + kg0 * 8;
    u16* AsW = As + wave * 512;
    u16* BsW = Bs + wave * 512;
    const int wm = (wave >> 1) * 64;
    const int wn = (wave & 1) * 64;
    const int fr = lane & 15;
    const int swz = (((lane >> 4) ^ ((fr >> 1) & 3))) * 8;
    f32x4 acc[4][4];
#pragma unroll
    for (int i = 0; i < 4; ++i)
#pragma unroll
        for (int j = 0; j < 4; ++j) acc[i][j] = (f32x4)0.0f;
    for (int kk = 0; kk < H_ / 32; ++kk) {
        gload_lds16(gA0, AsW); gload_lds16(gA1, AsW + 2048);
        gload_lds16(gB0, BsW); gload_lds16(gB1, BsW + 2048);
        gA0 += 32; gA1 += 32; gB0 += 32; gB1 += 32;
        __syncthreads();
        short8 a[4], b[4];
#pragma unroll
        for (int i = 0; i < 4; ++i) a[i] = *(const short8*)(As + (wm + i * 16 + fr) * 32 + swz);
#pragma unroll
        for (int i = 0; i < 4; ++i) b[i] = *(const short8*)(Bs + (wn + i * 16 + fr) * 32 + swz);
#pragma unroll
        for (int i = 0; i < 4; ++i)
#pragma unroll
            for (int j = 0; j < 4; ++j)
                acc[i][j] = __builtin_amdgcn_mfma_f32_16x16x32_bf16(a[i], b[j], acc[i][j], 0, 0, 0);
        __syncthreads();
    }
    const int cq = lane >> 4;
    const int cc = lane & 15;
#pragma unroll
    for (int i = 0; i < 4; ++i) {
#pragma unroll
        for (int r = 0; r < 4; ++r) {
            const int irow = mt * 128 + wm + i * 16 + cq * 4 + r;
            if (irow < count) {
                const int tok = ptok[irow];
                const float g = pgate[irow];
                float* yrow = y + (size_t)tok * OUT_;
#pragma unroll
                for (int j = 0; j < 4; ++j) {
                    const int gcol = nt * 128 + wn + j * 16 + cc;
                    yrow[gcol] += g * (acc[i][j][r] + b2_e[gcol]);
                }
            }
        }
    }
}

// ---------------------------------------------------------------------------
extern "C" void kernel_launch(void* const* d_in, const int* in_sizes, int n_in,
                              void* d_out, int out_size, void* d_ws, size_t ws_size,
                              hipStream_t stream)
{
    const float* x     = (const float*)d_in[0];
    const float* gamma = (const float*)d_in[1];
    const float* beta  = (const float*)d_in[2];
    const float* rw    = (const float*)d_in[3];
    const float* rb    = (const float*)d_in[4];
    const float* w1    = (const float*)d_in[5];
    const float* b1    = (const float*)d_in[6];
    const float* w2    = (const float*)d_in[7];
    const float* b2    = (const float*)d_in[8];
    float* y = (float*)d_out;

    char* ws = (char*)d_ws;
    const size_t xn_off   = 0;                         // 64 MB
    const size_t w1t_off  = 67108864;                  // 32 MB
    const size_t w2t_off  = 100663296;                 // 32 MB
    const size_t ptok_off = 134217728;                 // 1 MB
    const size_t pgat_off = 135266304;                 // 1 MB
    const size_t tidx_off = 136314880;                 // 128 KB
    const size_t tgat_off = 136445952;                 // 512 KB
    const size_t meta_off = 136970240;                 // 8 KB (incl desc)
    const size_t gcnt_off = 136978432;                 // 32 B
    const size_t h_off    = 137363456;                 // h chunk buffer

    u16*      xn        = (u16*)(ws + xn_off);
    u16*      w1t       = (u16*)(ws + w1t_off);
    u16*      w2t       = (u16*)(ws + w2t_off);
    int*      pair_tok  = (int*)(ws + ptok_off);
    float*    pair_gate = (float*)(ws + pgat_off);
    unsigned* topk_idx  = (unsigned*)(ws + tidx_off);
    float*    topk_gate = (float*)(ws + tgat_off);
    int*      meta      = (int*)(ws + meta_off);
    int*      gcount    = (int*)(ws + gcnt_off);
    u16*      h         = (u16*)(ws + h_off);

    hipMemsetAsync(gcount, 0, 32, stream);
    hipMemsetAsync(pair_tok, 0, (size_t)E_ * T_ * 4, stream);
    hipMemsetAsync(d_out, 0, (size_t)T_ * OUT_ * 4, stream);

    ln_router_kernel<<<T_ / 4, 256, 0, stream>>>(x, gamma, beta, rw, rb, xn, topk_idx, topk_gate);
    transpose_cvt_kernel<<<32768, 256, 0, stream>>>(w1, w2, w1t, w2t);
    pair_build_kernel<<<T_ / 256, 256, 0, stream>>>(topk_idx, topk_gate, pair_tok, pair_gate, gcount);

    // Chunked grouped path. CT capped at 192 tiles (96 MB h chunk) so the
    // h chunk stays L3-resident between gemm1 and gemm2 and the reused
    // buffer is re-dirtied before eviction (kills most h HBM write-back).
    // CT must be a multiple of 8 for the XCD-cohort swizzle.
    const size_t tile_bytes = (size_t)128 * H_ * 2;    // 512 KB / tile
    size_t avail = (ws_size > h_off) ? (ws_size - h_off) : 0;
    int CT = (int)(avail / tile_bytes);
    if (CT > 192) CT = 192;
    CT &= ~7;

    if (CT >= 64) {
        scan_kernel<<<1, 64, 0, stream>>>(gcount, meta);
        for (int base = 0; base < MAXTILES_; base += CT) {
            const int tiles = (MAXTILES_ - base < CT) ? (MAXTILES_ - base) : CT;
            gemm1_grouped<<<dim3(tiles * 16), 256, 0, stream>>>(
                xn, w1t, b1, pair_tok, gcount, meta, h, base);
            gemm2_grouped<<<dim3(tiles * 8), 256, 0, stream>>>(
                h, w2t, b2, pair_tok, pair_gate, gcount, meta, y, base);
        }
    } else {
        for (int e = 0; e < E_; ++e) {
            gemm1_kernel<<<dim3(H_ / 128, T_ / 128), 256, 0, stream>>>(
                xn, w1t + (size_t)e * H_ * D_, b1 + (size_t)e * H_,
                pair_tok + (size_t)e * T_, gcount + e, h);
            gemm2_kernel<<<dim3(OUT_ / 128, T_ / 128), 256, 0, stream>>>(
                h, w2t + (size_t)e * OUT_ * H_, b2 + (size_t)e * OUT_,
                pair_tok + (size_t)e * T_, pair_gate + (size_t)e * T_, gcount + e, y);
        }
    }
}